// Round 1
// baseline (290.542 us; speedup 1.0000x reference)
//
#include <hip/hip_runtime.h>
#include <math.h>

// FilterMLPBlock: y = irfft(rfft(x,axis=S,ortho)*w, ortho) ; out = LN_D(y + x)
// B=4096, S=64, D=256, F=33. The spectral filter is a per-channel (d) real
// circulant along S:  y[s,d] = sum_t k[d][(s-t)&63] * x[t,d]
// k[d][dlt] = (1/64)(wr0 + (-1)^dlt*wr32 + 2*sum_{f=1..31}(wr_f cos - wi_f sin)(2pi f dlt/64))
// (pocketfft c2r drops Im(DC) and Im(Nyquist) -> only wr0, wr32 enter.)

#define S_ 64
#define D_ 256
#define LSTR 257   // odd LDS row stride (floats): conflict-free col & row access

__global__ void precompute_k_kernel(const float* __restrict__ cw,
                                    float* __restrict__ k) {
    const int d   = threadIdx.x;   // 0..255
    const int dlt = blockIdx.x;    // 0..63
    // cw layout: [f][d][2] (re, im)
    float acc = cw[(0 * D_ + d) * 2 + 0];                       // wr[0,d]
    acc += ((dlt & 1) ? -1.f : 1.f) * cw[(32 * D_ + d) * 2 + 0]; // wr[32,d]*(-1)^dlt
    const float step = 6.28318530717958647692f / 64.f;
    #pragma unroll
    for (int f = 1; f <= 31; ++f) {
        int m = (f * dlt) & 63;            // exact arg reduction (period 64)
        float th = step * (float)m;
        float sn, cs;
        sincosf(th, &sn, &cs);
        float wr = cw[(f * D_ + d) * 2 + 0];
        float wi = cw[(f * D_ + d) * 2 + 1];
        acc += 2.f * (wr * cs - wi * sn);
    }
    k[dlt * D_ + d] = acc * (1.f / 64.f);  // layout k[dlt][d] -> coalesced loads
}

__global__ __launch_bounds__(256, 2)
void filter_ln_kernel(const float* __restrict__ x,
                      const float* __restrict__ k,
                      const float* __restrict__ gamma,
                      const float* __restrict__ beta,
                      float* __restrict__ out) {
    __shared__ float xs[S_ * LSTR];        // x tile, then reused for h = y + x
    __shared__ float psum[256];
    __shared__ float psumsq[256];
    __shared__ float mr[S_ * 2];           // per-row mean, rstd

    const int i = threadIdx.x;             // channel d for phases A/B/D
    const int b = blockIdx.x;
    const float* __restrict__ xb = x + (size_t)b * (S_ * D_);

    // ---- Phase A: stage x[64][256] into LDS (coalesced; stride-257 rows) ----
    #pragma unroll
    for (int t = 0; t < S_; ++t)
        xs[t * LSTR + i] = xb[t * D_ + i];

    // circulant kernel column for this d (L2-resident, coalesced)
    float kd[64];
    #pragma unroll
    for (int dl = 0; dl < 64; ++dl)
        kd[dl] = k[dl * D_ + i];

    __syncthreads();

    // ---- Phase B: per-channel circular conv along S (all-register FMAs) ----
    float y[64];
    #pragma unroll
    for (int s = 0; s < 64; ++s) y[s] = 0.f;
    #pragma unroll
    for (int t = 0; t < 64; ++t) {
        float xt = xs[t * LSTR + i];       // broadcast-free column read
        #pragma unroll
        for (int s = 0; s < 64; ++s)
            y[s] = fmaf(kd[(s - t) & 63], xt, y[s]);  // static reg indices
    }
    // residual: h = y + x  (thread only touches its own column -> no barrier)
    #pragma unroll
    for (int s = 0; s < 64; ++s)
        y[s] += xs[s * LSTR + i];
    // write h back into the tile (same column -> no cross-thread hazard)
    #pragma unroll
    for (int s = 0; s < 64; ++s)
        xs[s * LSTR + i] = y[s];

    __syncthreads();

    // ---- Phase C: LayerNorm stats over D per row s (4 partials per row) ----
    {
        const int s = i & 63, q = i >> 6;
        float s1 = 0.f, s2 = 0.f;
        #pragma unroll
        for (int j = 0; j < 64; ++j) {
            float v = xs[s * LSTR + q * 64 + j];  // odd stride -> conflict-free
            s1 += v;
            s2 = fmaf(v, v, s2);
        }
        psum[q * 64 + s]   = s1;
        psumsq[q * 64 + s] = s2;
    }
    __syncthreads();
    if (i < 64) {
        float s1 = psum[i] + psum[64 + i] + psum[128 + i] + psum[192 + i];
        float s2 = psumsq[i] + psumsq[64 + i] + psumsq[128 + i] + psumsq[192 + i];
        float mean = s1 * (1.f / 256.f);
        float var  = s2 * (1.f / 256.f) - mean * mean;
        mr[i * 2 + 0] = mean;
        mr[i * 2 + 1] = rsqrtf(var + 1e-12f);
    }
    __syncthreads();

    // ---- Phase D: normalize + affine + coalesced store ----
    const float g  = gamma[i];
    const float bt = beta[i];
    float* __restrict__ ob = out + (size_t)b * (S_ * D_);
    #pragma unroll
    for (int s = 0; s < 64; ++s) {
        float m = mr[s * 2 + 0];           // same-address broadcast reads
        float r = mr[s * 2 + 1];
        ob[s * D_ + i] = (y[s] - m) * r * g + bt;
    }
}

extern "C" void kernel_launch(void* const* d_in, const int* in_sizes, int n_in,
                              void* d_out, int out_size, void* d_ws, size_t ws_size,
                              hipStream_t stream) {
    const float* x     = (const float*)d_in[0];
    const float* cw    = (const float*)d_in[1];   // [1,33,256,2]
    const float* gamma = (const float*)d_in[2];
    const float* beta  = (const float*)d_in[3];
    float* out = (float*)d_out;
    float* k   = (float*)d_ws;                    // 64*256*4 = 64 KB scratch

    precompute_k_kernel<<<64, 256, 0, stream>>>(cw, k);
    filter_ln_kernel<<<4096, 256, 0, stream>>>(x, k, gamma, beta, out);
}